// Round 4
// baseline (2230.287 us; speedup 1.0000x reference)
//
#include <hip/hip_runtime.h>
#include <math.h>

#define NPATCH 100000
#define CDIM   256
#define NMOOD  64
#define NGENRE 256
#define NSUB   512
#define NLBL   832          // 64+256+512
#define NCHUNK 39
#define CHUNK  2624         // 39*2624 = 102336 >= 100000
#define BLK    64
#define KC     32
#define KTOP   9
#define KP     12           // per-(label,chunk) partial list size

// ---------------- serial top-k insert (ascending by (val,idx)) --------------

template <int K>
__device__ __forceinline__ void tk_insert(float (&v)[K], int (&ii)[K],
                                          float s, int idx) {
  if (s < v[K - 1] || (s == v[K - 1] && idx < ii[K - 1])) {
    v[K - 1] = s; ii[K - 1] = idx;
#pragma unroll
    for (int t = K - 1; t > 0; --t) {
      bool sw = (v[t] < v[t - 1]) || (v[t] == v[t - 1] && ii[t] < ii[t - 1]);
      if (sw) {
        float fv = v[t]; v[t] = v[t - 1]; v[t - 1] = fv;
        int fi = ii[t]; ii[t] = ii[t - 1]; ii[t - 1] = fi;
      }
    }
  }
}

// ------ numpy-pairwise sum of squares over 256 contiguous floats ------------
// Replicates np.sum(x*x, axis=-1) rounding exactly: products individually
// rounded; 2 blocks of 128, each with 8 strided accumulators + fixed combine
// tree; block results added. No FMA contraction (explicit _rn intrinsics).

__device__ float np_sq256(const float* a) {
  float b0, b1;
  {
    float r[8];
#pragma unroll
    for (int i = 0; i < 8; ++i) { float x = a[i]; r[i] = __fmul_rn(x, x); }
    for (int j = 8; j < 128; j += 8)
#pragma unroll
      for (int i = 0; i < 8; ++i) {
        float x = a[j + i];
        r[i] = __fadd_rn(r[i], __fmul_rn(x, x));
      }
    b0 = __fadd_rn(__fadd_rn(__fadd_rn(r[0], r[1]), __fadd_rn(r[2], r[3])),
                   __fadd_rn(__fadd_rn(r[4], r[5]), __fadd_rn(r[6], r[7])));
  }
  {
    float r[8];
#pragma unroll
    for (int i = 0; i < 8; ++i) { float x = a[128 + i]; r[i] = __fmul_rn(x, x); }
    for (int j = 8; j < 128; j += 8)
#pragma unroll
      for (int i = 0; i < 8; ++i) {
        float x = a[128 + j + i];
        r[i] = __fadd_rn(r[i], __fmul_rn(x, x));
      }
    b1 = __fadd_rn(__fadd_rn(__fadd_rn(r[0], r[1]), __fadd_rn(r[2], r[3])),
                   __fadd_rn(__fadd_rn(r[4], r[5]), __fadd_rn(r[6], r[7])));
  }
  return __fadd_rn(b0, b1);
}

// d2 key with numpy's expression-tree rounding: (ln - 2*dot) + pn
__device__ __forceinline__ float np_key(float ln, float dot, float pn) {
  return __fadd_rn(__fsub_rn(ln, __fmul_rn(2.f, dot)), pn);
}

// ---------------- kernel 1: concat labels into one (832,256) matrix ---------

__global__ void k_concat_labels(const float* __restrict__ mood,
                                const float* __restrict__ genre,
                                const float* __restrict__ sub,
                                float* __restrict__ lbl) {
  int i = blockIdx.x * 256 + threadIdx.x;
  if (i < NMOOD * CDIM) lbl[i] = mood[i];
  else if (i < (NMOOD + NGENRE) * CDIM) lbl[i] = genre[i - NMOOD * CDIM];
  else lbl[i] = sub[i - (NMOOD + NGENRE) * CDIM];
}

// ---------------- kernel 2: numpy-pairwise row norms -------------------------

__global__ void k_norms_np(const float* __restrict__ m, int n,
                           float* __restrict__ out) {
  int i = blockIdx.x * blockDim.x + threadIdx.x;
  int stride = gridDim.x * blockDim.x;
  for (; i < n; i += stride) out[i] = np_sq256(m + (size_t)i * CDIM);
}

// ---------------- kernel 3: dot GEMM (sequential-k fma) + top-12 screen -----
// grid (NCHUNK, 13); block 256 (16x16 threads, 4x4 register tile).
// acc accumulates k ascending 0..255 in a single fmaf chain per (l,p) —
// matches BLAS sgemm micro-kernel rounding.

__global__ void k_screen(const float* __restrict__ lbl,
                         const float* __restrict__ patch,
                         const float* __restrict__ pnorm,
                         const float* __restrict__ lnorm,
                         float* __restrict__ part_s,
                         int* __restrict__ part_i) {
  __shared__ float Asm[KC][BLK];
  __shared__ float Bsm[KC][BLK];
  __shared__ float sc[BLK][BLK + 1];
  const int tid = threadIdx.x;
  const int tr = tid >> 4, tc = tid & 15;
  const int lbase = blockIdx.y * BLK;
  const int chunk = blockIdx.x;
  const int p0 = chunk * CHUNK;
  const int p1 = (p0 + CHUNK < NPATCH) ? p0 + CHUNK : NPATCH;

  float tv[KP]; int ti[KP];
#pragma unroll
  for (int j = 0; j < KP; ++j) { tv[j] = INFINITY; ti[j] = 0x7fffffff; }
  const float ln = (tid < BLK) ? lnorm[lbase + tid] : 0.f;

  const int sl = tid >> 2;
  const int skq = (tid & 3) * 4;

  for (int pt = p0; pt < p1; pt += BLK) {
    float acc[4][4];
#pragma unroll
    for (int a = 0; a < 4; ++a)
#pragma unroll
      for (int b = 0; b < 4; ++b) acc[a][b] = 0.f;

    for (int kc = 0; kc < CDIM; kc += KC) {
      __syncthreads();
      {
        const float* arow = &lbl[(size_t)(lbase + sl) * CDIM + kc];
        float4 va0 = *(const float4*)(arow + skq);
        float4 va1 = *(const float4*)(arow + 16 + skq);
        Asm[skq + 0][sl] = va0.x; Asm[skq + 1][sl] = va0.y;
        Asm[skq + 2][sl] = va0.z; Asm[skq + 3][sl] = va0.w;
        Asm[16 + skq + 0][sl] = va1.x; Asm[16 + skq + 1][sl] = va1.y;
        Asm[16 + skq + 2][sl] = va1.z; Asm[16 + skq + 3][sl] = va1.w;
        int p = pt + sl;
        float4 vb0 = make_float4(0.f, 0.f, 0.f, 0.f), vb1 = vb0;
        if (p < p1) {
          const float* brow = &patch[(size_t)p * CDIM + kc];
          vb0 = *(const float4*)(brow + skq);
          vb1 = *(const float4*)(brow + 16 + skq);
        }
        Bsm[skq + 0][sl] = vb0.x; Bsm[skq + 1][sl] = vb0.y;
        Bsm[skq + 2][sl] = vb0.z; Bsm[skq + 3][sl] = vb0.w;
        Bsm[16 + skq + 0][sl] = vb1.x; Bsm[16 + skq + 1][sl] = vb1.y;
        Bsm[16 + skq + 2][sl] = vb1.z; Bsm[16 + skq + 3][sl] = vb1.w;
      }
      __syncthreads();
#pragma unroll
      for (int k = 0; k < KC; ++k) {
        float4 a4 = *(const float4*)&Asm[k][tr * 4];
        float4 b4 = *(const float4*)&Bsm[k][tc * 4];
        const float av[4] = {a4.x, a4.y, a4.z, a4.w};
        const float bv[4] = {b4.x, b4.y, b4.z, b4.w};
#pragma unroll
        for (int a = 0; a < 4; ++a)
#pragma unroll
          for (int b = 0; b < 4; ++b) acc[a][b] = fmaf(av[a], bv[b], acc[a][b]);
      }
    }
#pragma unroll
    for (int a = 0; a < 4; ++a)
#pragma unroll
      for (int b = 0; b < 4; ++b) sc[tr * 4 + a][tc * 4 + b] = acc[a][b];
    __syncthreads();
    if (tid < BLK) {
      for (int c = 0; c < BLK; ++c) {
        int p = pt + c;
        if (p < p1) tk_insert<KP>(tv, ti, np_key(ln, sc[tid][c], pnorm[p]), p);
      }
    }
  }

  if (tid < BLK) {
    int lab = lbase + tid;
    size_t base = ((size_t)lab * NCHUNK + chunk) * KP;
#pragma unroll
    for (int j = 0; j < KP; ++j) { part_s[base + j] = tv[j]; part_i[base + j] = ti[j]; }
  }
}

// ---------------- kernel 4: merge chunk partials (f32 keys) + max-agg -------

__global__ void k_merge_patch(const float* __restrict__ part_s,
                              const int* __restrict__ part_i,
                              const float* __restrict__ patch,
                              const float* __restrict__ lbl,
                              float* __restrict__ ctx) {
  const int lab = blockIdx.x;
  const int tid = threadIdx.x;
  __shared__ float cv[16][KP];
  __shared__ int ci[16][KP];
  __shared__ int nb[KTOP];

  const int total = NCHUNK * KP;  // 468
  if (tid < 16) {
    float v[KP]; int ii[KP];
#pragma unroll
    for (int j = 0; j < KP; ++j) { v[j] = INFINITY; ii[j] = 0x7fffffff; }
    for (int e = tid; e < total; e += 16)
      tk_insert<KP>(v, ii, part_s[(size_t)lab * total + e],
                    part_i[(size_t)lab * total + e]);
#pragma unroll
    for (int j = 0; j < KP; ++j) { cv[tid][j] = v[j]; ci[tid][j] = ii[j]; }
  }
  __syncthreads();
  if (tid == 0) {
    float v[KP]; int ii[KP];
#pragma unroll
    for (int j = 0; j < KP; ++j) { v[j] = INFINITY; ii[j] = 0x7fffffff; }
    for (int t = 0; t < 16; ++t)
      for (int j = 0; j < KP; ++j) tk_insert<KP>(v, ii, cv[t][j], ci[t][j]);
#pragma unroll
    for (int j = 0; j < KTOP; ++j) nb[j] = ii[j];
  }
  __syncthreads();
  float l = lbl[(size_t)lab * CDIM + tid];
  float mx = -INFINITY;
#pragma unroll
  for (int j = 0; j < KTOP; ++j)
    mx = fmaxf(mx, patch[(size_t)nb[j] * CDIM + tid]);
  ctx[(size_t)lab * CDIM + tid] = mx - l;
}

// ---------------- kernel 5: small label->label agg (np-f32 semantics) -------

__global__ void k_small_agg(const float* __restrict__ lbl_rows,
                            const float* __restrict__ tgt, int M, int k,
                            float* __restrict__ ctx) {
  const int row = blockIdx.x;
  const int tid = threadIdx.x;
  __shared__ float lsh[CDIM];
  __shared__ float skey[256];
  __shared__ float lns;
  __shared__ int nb[4];
  lsh[tid] = lbl_rows[(size_t)row * CDIM + tid];
  __syncthreads();
  if (tid == 0) lns = np_sq256(lsh);
  __syncthreads();
  float key = INFINITY;
  if (tid < M) {
    const float* trow = &tgt[(size_t)tid * CDIM];
    float tn = np_sq256(trow);
    float dot = 0.f;
    for (int c = 0; c < CDIM; ++c) dot = fmaf(lsh[c], trow[c], dot);
    key = np_key(lns, dot, tn);
  }
  skey[tid] = key;
  __syncthreads();
  if (tid == 0) {
    for (int t = 0; t < k; ++t) {
      float best = INFINITY; int bi = 0;
      for (int j = 0; j < M; ++j)
        if (skey[j] < best) { best = skey[j]; bi = j; }  // strict < => lowest idx tie
      nb[t] = bi; skey[bi] = INFINITY;
    }
  }
  __syncthreads();
  float mx = -INFINITY;
  for (int t = 0; t < k; ++t) mx = fmaxf(mx, tgt[(size_t)nb[t] * CDIM + tid]);
  ctx[(size_t)row * CDIM + tid] = mx - lsh[tid];
}

// ---------------- kernel 6: linear(concat) + residual + LayerNorm (f64) -----

__device__ __forceinline__ double block_sum_256d(double x, double* red) {
#pragma unroll
  for (int m = 32; m >= 1; m >>= 1) x += __shfl_xor(x, m);
  int wid = threadIdx.x >> 6, lane = threadIdx.x & 63;
  if (lane == 0) red[wid] = x;
  __syncthreads();
  double s = red[0] + red[1] + red[2] + red[3];
  __syncthreads();
  return s;
}

__global__ void k_level_out(const float* __restrict__ emb,
                            const float* __restrict__ c1,
                            const float* __restrict__ c2,
                            const float* __restrict__ c3, int nseg,
                            const float* __restrict__ W,
                            const float* __restrict__ bias,
                            const float* __restrict__ gamma,
                            const float* __restrict__ beta,
                            float* __restrict__ out) {
  __shared__ float xs[4 * CDIM];
  __shared__ double red[4];
  const int row = blockIdx.x, ch = threadIdx.x;
  float e = emb[(size_t)row * CDIM + ch];
  xs[ch] = e;
  if (nseg > 1) xs[CDIM + ch] = c1[(size_t)row * CDIM + ch];
  if (nseg > 2) xs[2 * CDIM + ch] = c2[(size_t)row * CDIM + ch];
  if (nseg > 3) xs[3 * CDIM + ch] = c3[(size_t)row * CDIM + ch];
  __syncthreads();
  const int F = nseg * CDIM;
  double y = (double)e + (double)bias[ch];
#pragma unroll 4
  for (int j = 0; j < F; ++j)
    y += (double)xs[j] * (double)W[(size_t)j * CDIM + ch];
  double mu = block_sum_256d(y, red) * (1.0 / 256.0);
  double d = y - mu;
  double var = block_sum_256d(d * d, red) * (1.0 / 256.0);
  out[(size_t)row * CDIM + ch] =
      (float)(d / sqrt(var + 1e-5) * (double)gamma[ch] + (double)beta[ch]);
}

// ---------------- launch ----------------------------------------------------

extern "C" void kernel_launch(void* const* d_in, const int* in_sizes, int n_in,
                              void* d_out, int out_size, void* d_ws, size_t ws_size,
                              hipStream_t stream) {
  const float* patch     = (const float*)d_in[0];
  const float* mood_emb  = (const float*)d_in[1];
  const float* genre_emb = (const float*)d_in[2];
  const float* sub_emb   = (const float*)d_in[3];
  const float* Wm_w = (const float*)d_in[4];
  const float* Wm_b = (const float*)d_in[5];
  const float* Wg_w = (const float*)d_in[6];
  const float* Wg_b = (const float*)d_in[7];
  const float* Ws_w = (const float*)d_in[8];
  const float* Ws_b = (const float*)d_in[9];
  const float* lnm_g = (const float*)d_in[10];
  const float* lnm_b = (const float*)d_in[11];
  const float* lng_g = (const float*)d_in[12];
  const float* lng_b = (const float*)d_in[13];
  const float* lns_g = (const float*)d_in[14];
  const float* lns_b = (const float*)d_in[15];
  float* out = (float*)d_out;

  float* ws = (float*)d_ws;
  float* lbl    = ws;                                   // 212992
  float* pnorm  = lbl + NLBL * CDIM;                    // 100352
  float* lnorm  = pnorm + 100352;                       // 1024
  float* part_s = lnorm + 1024;                         // 832*39*12 = 389376
  int*   part_i = (int*)(part_s + NLBL * NCHUNK * KP);  // 389376
  float* ctx_all = part_s + 2 * NLBL * NCHUNK * KP;     // 212992
  float* ctx_gm  = ctx_all + NLBL * CDIM;               // 65536
  float* ctx_sm  = ctx_gm + NGENRE * CDIM;              // 131072
  float* ctx_sg  = ctx_sm + NSUB * CDIM;                // 131072

  k_concat_labels<<<NLBL, 256, 0, stream>>>(mood_emb, genre_emb, sub_emb, lbl);
  k_norms_np<<<512, 256, 0, stream>>>(patch, NPATCH, pnorm);
  k_norms_np<<<4, 256, 0, stream>>>(lbl, NLBL, lnorm);
  dim3 gscr(NCHUNK, NLBL / BLK);
  k_screen<<<gscr, 256, 0, stream>>>(lbl, patch, pnorm, lnorm, part_s, part_i);
  k_merge_patch<<<NLBL, 256, 0, stream>>>(part_s, part_i, patch, lbl, ctx_all);
  // mood
  k_level_out<<<NMOOD, 256, 0, stream>>>(mood_emb, ctx_all, nullptr, nullptr, 2,
                                         Wm_w, Wm_b, lnm_g, lnm_b, out);
  // genre
  k_small_agg<<<NGENRE, 256, 0, stream>>>(genre_emb, out, NMOOD, 4, ctx_gm);
  k_level_out<<<NGENRE, 256, 0, stream>>>(genre_emb, ctx_all + NMOOD * CDIM, ctx_gm,
                                          nullptr, 3, Wg_w, Wg_b, lng_g, lng_b,
                                          out + NMOOD * CDIM);
  // sub
  k_small_agg<<<NSUB, 256, 0, stream>>>(sub_emb, out, NMOOD, 3, ctx_sm);
  k_small_agg<<<NSUB, 256, 0, stream>>>(sub_emb, out + NMOOD * CDIM, NGENRE, 4, ctx_sg);
  k_level_out<<<NSUB, 256, 0, stream>>>(sub_emb, ctx_all + (NMOOD + NGENRE) * CDIM,
                                        ctx_sm, ctx_sg, 4, Ws_w, Ws_b, lns_g, lns_b,
                                        out + NMOOD * CDIM + NGENRE * CDIM);
}